// Round 14
// baseline (1235.606 us; speedup 1.0000x reference)
//
#include <hip/hip_runtime.h>
#include <string.h>

#define TT 512
#define BB 256
#define CC 65
#define HALFC 32
#define HID 128
#define ODIM 10

typedef _Float16 half2_t __attribute__((ext_vector_type(2)));
typedef _Float16 half8_t __attribute__((ext_vector_type(8)));

// tanh(x) = 2/(1+e^{-2x}) - 1
__device__ __forceinline__ float ftanh(float x) {
  float u = __builtin_amdgcn_exp2f(x * -2.885390082f);
  return fmaf(2.f, __builtin_amdgcn_rcpf(1.f + u), -1.f);
}
// sigmoid(x) = 1/(1+e^{-x})
__device__ __forceinline__ float fsig(float x) {
  float u = __builtin_amdgcn_exp2f(x * -1.442695041f);
  return __builtin_amdgcn_rcpf(1.f + u);
}

// pack two f32 -> half2 (v_cvt_pkrtz_f16_f32)
__device__ __forceinline__ half2_t h2cvt(float a, float b) {
  auto r = __builtin_amdgcn_cvt_pkrtz(a, b);
  half2_t o;
  memcpy(&o, &r, sizeof(o));
  return o;
}

__device__ __forceinline__ float fdot2h(half2_t a, half2_t b, float c) {
  return __builtin_amdgcn_fdot2(a, b, c, false);
}

template <int CTRL>
__device__ __forceinline__ float dpp_add(float x) {
  return x + __int_as_float(__builtin_amdgcn_update_dpp(
      0, __float_as_int(x), CTRL, 0xF, 0xF, true));
}
// 2-lane subgroup sum via row_shl:1: dest[i] = src[i]+src[i+1]; valid (lane&1)==0.
__device__ __forceinline__ float red2(float x) {
  return dpp_add<0x101>(x);  // row_shl:1
}

// Raw barrier: drain LDS ops, no vmcnt drain (global loads stay in flight).
__device__ __forceinline__ void block_sync_lds() {
  asm volatile("s_waitcnt lgkmcnt(0)" ::: "memory");
  __builtin_amdgcn_s_barrier();
  asm volatile("" ::: "memory");
}
__device__ __forceinline__ void vm_wait0() {
  asm volatile("s_waitcnt vmcnt(0)" ::: "memory");
}

// Per-t scalars: idx (int bits), fr, td, tsub
__global__ void prep0(const float* __restrict__ times, float4* __restrict__ si,
                      int* __restrict__ anyobs) {
  __shared__ float ts[TT];
  int t = threadIdx.x;
  ts[t] = times[t];
  __syncthreads();
  float tv = ts[t];
  int cnt = 0;
  for (int jj = 0; jj < TT; ++jj) cnt += (tv > ts[jj]) ? 1 : 0;
  int idx = cnt - 1;
  idx = min(max(idx, 0), TT - 2);
  float4 o;
  o.x = __int_as_float(idx);
  o.y = tv - ts[idx];
  o.z = (t == 0) ? 0.f : (tv - ts[t - 1]);
  o.w = (t == 0) ? ts[0] : ts[t - 1];
  si[t] = o;
  anyobs[t] = 0;
}

// obs[b,t] = max over diffed channels 1..32 > 0.5 ; anyobs[t] = OR over b
__global__ void prep_obs(const float* __restrict__ ca, const float* __restrict__ cb,
                         const float* __restrict__ cc2, const float* __restrict__ cd,
                         const float4* __restrict__ si, int* __restrict__ anyobs,
                         unsigned char* __restrict__ obs) {
  int grp = blockIdx.x * (blockDim.x >> 5) + (threadIdx.x >> 5);
  int lane = threadIdx.x & 31;
  int t = grp & (TT - 1);
  int b = grp / TT;
  int ch = 1 + lane;
  float4 s = si[t];
  int idx = __float_as_int(s.x);
  float fr = s.y;
  size_t base = ((size_t)b * (TT - 1) + idx) * CC + ch;
  float f3 = fr / 3.f;
  float v = ca[base] + (cb[base] + (0.5f * cc2[base] + cd[base] * f3) * fr) * fr;
  float D = v;
  if (t >= 1) {
    float4 sp = si[t - 1];
    int idxp = __float_as_int(sp.x);
    float frp = sp.y;
    size_t basep = ((size_t)b * (TT - 1) + idxp) * CC + ch;
    float f3p = frp / 3.f;
    float vp = ca[basep] + (cb[basep] + (0.5f * cc2[basep] + cd[basep] * f3p) * frp) * frp;
    D = v - vp;
  }
  float m = D;
  #pragma unroll
  for (int off = 16; off >= 1; off >>= 1) m = fmaxf(m, __shfl_xor(m, off));
  if (lane == 0) {
    unsigned char o = (m > 0.5f) ? (unsigned char)1 : (unsigned char)0;
    obs[(size_t)b * TT + t] = o;
    if (o) atomicOr(&anyobs[t], 1);
  }
}

// One block per batch element. 128 threads = 2 waves (minimal barrier domain).
// Lane (p=lane>>1, kk=lane&1) owns output pair s = wv*32+p over k-slice
// [64kk, 64kk+64). f16 weights+state via v_dot2; x channel 0 in f32.
// Schedule identical to R13: spline at loop top (prev-step prefetch),
// x-partials in stage-2 shadow, GRU skipped when ob==0.
__launch_bounds__(128, 1)
__global__ void ode_main(
    const float* __restrict__ ca, const float* __restrict__ cb,
    const float* __restrict__ cc2, const float* __restrict__ cd,
    const int* __restrict__ final_index,
    const float* __restrict__ Wr, const float* __restrict__ br,
    const float* __restrict__ Wz, const float* __restrict__ bz,
    const float* __restrict__ Wxn, const float* __restrict__ bxn,
    const float* __restrict__ Whn, const float* __restrict__ bhn,
    const float* __restrict__ Wode, const float* __restrict__ bode,
    const float* __restrict__ Wlin, const float* __restrict__ blin,
    const float4* __restrict__ si, const int* __restrict__ anyobs,
    const unsigned char* __restrict__ obsArr,
    float* __restrict__ out)
{
  __shared__ alignas(16) half2_t hS2[HID / 2];
  __shared__ alignas(16) half2_t vA2[HID / 2];
  __shared__ alignas(16) half2_t vB2[HID / 2];
  __shared__ alignas(16) _Float16 xh[HALFC];
  __shared__ float xs0f;
  __shared__ alignas(16) float4 siL[TT];
  __shared__ unsigned char flagL[TT];

  const int tid = threadIdx.x;
  const int b = blockIdx.x;
  const int lane = tid & 63;
  const int wv = tid >> 6;       // 0..1
  const int p = lane >> 1;       // 0..31
  const int kk = lane & 1;       // 0..1
  const int s = wv * 32 + p;     // output pair 0..63
  const int j0 = 2 * s;
  const int wbyte = 4 * s;       // write byte offset (half2)

  // ---- h-matvec weights f16: rows [64kk, 64kk+64), 2 cols ----
  half2_t wodeH[64], whnH[64], wrhH[64], wzhH[64];
  #pragma unroll
  for (int i = 0; i < 32; ++i) {
    const int r0 = 64 * kk + 2 * i, r1 = r0 + 1;
    float2 q0, q1;
    q0 = *(const float2*)&Wode[r0 * HID + j0];
    q1 = *(const float2*)&Wode[r1 * HID + j0];
    wodeH[2*i] = h2cvt(q0.x, q1.x); wodeH[2*i+1] = h2cvt(q0.y, q1.y);
    q0 = *(const float2*)&Whn[r0 * HID + j0];
    q1 = *(const float2*)&Whn[r1 * HID + j0];
    whnH[2*i] = h2cvt(q0.x, q1.x); whnH[2*i+1] = h2cvt(q0.y, q1.y);
    q0 = *(const float2*)&Wr[(HALFC + r0) * HID + j0];
    q1 = *(const float2*)&Wr[(HALFC + r1) * HID + j0];
    wrhH[2*i] = h2cvt(q0.x, q1.x); wrhH[2*i+1] = h2cvt(q0.y, q1.y);
    q0 = *(const float2*)&Wz[(HALFC + r0) * HID + j0];
    q1 = *(const float2*)&Wz[(HALFC + r1) * HID + j0];
    wzhH[2*i] = h2cvt(q0.x, q1.x); wzhH[2*i+1] = h2cvt(q0.y, q1.y);
  }
  // x-part weights f16 over channels [16kk, 16kk+16): [i] out j0, [8+i] out j0+1
  half2_t wrxH[16], wzxH[16], wxnH[16];
  #pragma unroll
  for (int i = 0; i < 8; ++i) {
    const int c0 = 16 * kk + 2 * i, c1 = c0 + 1;
    float2 q0, q1;
    q0 = *(const float2*)&Wr[c0 * HID + j0];
    q1 = *(const float2*)&Wr[c1 * HID + j0];
    wrxH[i] = h2cvt(q0.x, q1.x); wrxH[8+i] = h2cvt(q0.y, q1.y);
    q0 = *(const float2*)&Wz[c0 * HID + j0];
    q1 = *(const float2*)&Wz[c1 * HID + j0];
    wzxH[i] = h2cvt(q0.x, q1.x); wzxH[8+i] = h2cvt(q0.y, q1.y);
    q0 = *(const float2*)&Wxn[c0 * HID + j0];
    q1 = *(const float2*)&Wxn[c1 * HID + j0];
    wxnH[i] = h2cvt(q0.x, q1.x); wxnH[8+i] = h2cvt(q0.y, q1.y);
  }
  // channel 0 (dt channel, large): zero f16 weight, add in f32
  float wr0a = 0.f, wr0b = 0.f, wz0a = 0.f, wz0b = 0.f, wx0a = 0.f, wx0b = 0.f;
  if (kk == 0) {
    wrxH[0][0] = (_Float16)0.f; wrxH[8][0] = (_Float16)0.f;
    wzxH[0][0] = (_Float16)0.f; wzxH[8][0] = (_Float16)0.f;
    wxnH[0][0] = (_Float16)0.f; wxnH[8][0] = (_Float16)0.f;
    wr0a = Wr[j0];  wr0b = Wr[j0 + 1];
    wz0a = Wz[j0];  wz0b = Wz[j0 + 1];
    wx0a = Wxn[j0]; wx0b = Wxn[j0 + 1];
  }
  float bo0, bo1, bh0, bh1, br0, br1, bz0, bz1, bx0, bx1;
  { float2 q;
    q = *(const float2*)&bode[j0]; bo0 = q.x; bo1 = q.y;
    q = *(const float2*)&bhn [j0]; bh0 = q.x; bh1 = q.y;
    q = *(const float2*)&br  [j0]; br0 = q.x; br1 = q.y;
    q = *(const float2*)&bz  [j0]; bz0 = q.x; bz1 = q.y;
    q = *(const float2*)&bxn [j0]; bx0 = q.x; bx1 = q.y;
  }
  const int fidx = final_index[b];

  // ---- stage per-step metadata into LDS (one-time; 4 sweeps of 128) ----
  #pragma unroll
  for (int it = 0; it < 4; ++it) {
    const int tt = tid + it * 128;
    siL[tt] = si[tt];
    const int ao = anyobs[tt];
    const unsigned char o = obsArr[(size_t)b * TT + tt];
    flagL[tt] = (unsigned char)((ao ? 1 : 0) | (o ? 2 : 0));
  }
  if (tid < HID / 2) {
    const half2_t z2 = {(_Float16)0.f, (_Float16)0.f};
    hS2[tid] = z2; vA2[tid] = z2; vB2[tid] = z2;
  }
  if (tid < HALFC) xh[tid] = (_Float16)0.f;
  if (tid == 0) xs0f = 0.f;
  float hj0 = 0.f, hj1 = 0.f;  // fp32 master h, valid on kk==0 lanes
  float dtv = 0.f;             // valid on tid==0
  block_sync_lds();

  // matvec over linear f16 LDS vector: 8 b128 reads (2-addr broadcast),
  // 64 dot2 in 4 chains, red2.
  auto mv = [&](const half2_t* __restrict__ buf, const half2_t (&w)[64],
                float& o0, float& o1) {
    half2_t v2[32];
    #pragma unroll
    for (int q = 0; q < 8; ++q) {
      const half8_t x8 = *(const half8_t*)((const char*)buf + 128 * kk + 16 * q);
      v2[4*q+0] = __builtin_shufflevector(x8, x8, 0, 1);
      v2[4*q+1] = __builtin_shufflevector(x8, x8, 2, 3);
      v2[4*q+2] = __builtin_shufflevector(x8, x8, 4, 5);
      v2[4*q+3] = __builtin_shufflevector(x8, x8, 6, 7);
    }
    float a0 = 0.f, a1 = 0.f, b0 = 0.f, b1 = 0.f;
    #pragma unroll
    for (int i = 0; i < 16; ++i) {
      a0 = fdot2h(v2[i],      w[2*i],        a0);
      a1 = fdot2h(v2[i],      w[2*i+1],      a1);
      b0 = fdot2h(v2[16 + i], w[2*(16+i)],   b0);
      b1 = fdot2h(v2[16 + i], w[2*(16+i)+1], b1);
    }
    o0 = red2(a0 + b0);
    o1 = red2(a1 + b1);
  };

  const int xch = wv * 16 + lane;   // valid when lane < 16
  const bool xlane = (lane < 16);

  float4 sv4 = siL[0];
  int flg = flagL[0];

  // issue x-coeff loads for t=0
  float xa = 0.f, xb = 0.f, xc = 0.f, xd = 0.f;
  float ya = 0.f, yb = 0.f, yc = 0.f, yd = 0.f;
  if (xlane) {
    const size_t base = ((size_t)b * (TT - 1) + __float_as_int(sv4.x)) * CC;
    const int ch = 33 + xch;
    xa = ca[base + ch]; xb = cb[base + ch]; xc = cc2[base + ch]; xd = cd[base + ch];
    if (tid == 0) { ya = ca[base]; yb = cb[base]; yc = cc2[base]; yd = cd[base]; }
  }

  for (int t = 0; ; ++t) {
    const float fr = sv4.y, td = sv4.z, tsub = sv4.w;
    const bool doGru = (flg & 2) != 0;   // block-uniform

    // ---- loop top: spline for step t (loads issued last iter) ----
    float xdelta = 0.f;
    vm_wait0();
    if (xlane) {
      const float f3 = fr * (1.f / 3.f);
      float sv = xa + (xb + (0.5f * xc + xd * f3) * fr) * fr;
      if (tid == 0) {
        const float s0 = ya + (yb + (0.5f * yc + yd * f3) * fr) * fr;
        xdelta = s0 - tsub;
        sv += dtv;       // Xp[:,0] += dt (dtv final from step t-1)
        xs0f = sv;
      }
      xh[xch] = (_Float16)sv;
    }

    // ---- prefetch next step's metadata + issue next x-coeff loads ----
    const int tn = (t < TT - 1) ? t + 1 : t;
    const float4 sv4N = siL[tn];
    const int flgN = flagL[tn];
    if (xlane) {
      const size_t base = ((size_t)b * (TT - 1) + __float_as_int(sv4N.x)) * CC;
      const int ch = 33 + xch;
      xa = ca[base + ch]; xb = cb[base + ch]; xc = cc2[base + ch]; xd = cd[base + ch];
      if (tid == 0) { ya = ca[base]; yb = cb[base]; yc = cc2[base]; yd = cd[base]; }
    }

    // x-matvec partials (computed in stage-2 shadow when t>0)
    float rxp0 = 0.f, rxp1 = 0.f, zxp0 = 0.f, zxp1 = 0.f, xxp0 = 0.f, xxp1 = 0.f;

    auto xpartials = [&]() {
      half2_t xv2[8];
      #pragma unroll
      for (int q = 0; q < 2; ++q) {
        const half8_t x8 = *(const half8_t*)((const char*)xh + 32 * kk + 16 * q);
        xv2[4*q+0] = __builtin_shufflevector(x8, x8, 0, 1);
        xv2[4*q+1] = __builtin_shufflevector(x8, x8, 2, 3);
        xv2[4*q+2] = __builtin_shufflevector(x8, x8, 4, 5);
        xv2[4*q+3] = __builtin_shufflevector(x8, x8, 6, 7);
      }
      #pragma unroll
      for (int i = 0; i < 8; ++i) {
        rxp0 = fdot2h(xv2[i], wrxH[i],   rxp0);
        rxp1 = fdot2h(xv2[i], wrxH[8+i], rxp1);
        zxp0 = fdot2h(xv2[i], wzxH[i],   zxp0);
        zxp1 = fdot2h(xv2[i], wzxH[8+i], zxp1);
        xxp0 = fdot2h(xv2[i], wxnH[i],   xxp0);
        xxp1 = fdot2h(xv2[i], wxnH[8+i], xxp1);
      }
      if (kk == 0) {
        const float x0 = xs0f;
        rxp0 = fmaf(x0, wr0a, rxp0); rxp1 = fmaf(x0, wr0b, rxp1);
        zxp0 = fmaf(x0, wz0a, zxp0); zxp1 = fmaf(x0, wz0b, zxp1);
        xxp0 = fmaf(x0, wx0a, xxp0); xxp1 = fmaf(x0, wx0b, xxp1);
      }
    };

    if (t > 0) {
      const float htd = 0.5f * td;
      float p0, p1, k0, k1, ks0, ks1;
      // stage 1: k1 = f(h)
      mv(hS2, wodeH, p0, p1);
      k0 = ftanh(p0 + bo0); k1 = ftanh(p1 + bo1);
      ks0 = k0; ks1 = k1;
      if (kk == 0)
        *(half2_t*)((char*)vA2 + wbyte) =
            h2cvt(fmaf(htd, k0, hj0), fmaf(htd, k1, hj1));
      block_sync_lds();   // publishes vA2 AND xh/xs0f
      if (doGru) xpartials();   // in stage-2's shadow
      // stage 2: k2 = f(h + td/2 k1)
      mv(vA2, wodeH, p0, p1);
      k0 = ftanh(p0 + bo0); k1 = ftanh(p1 + bo1);
      ks0 = fmaf(2.f, k0, ks0); ks1 = fmaf(2.f, k1, ks1);
      if (kk == 0)
        *(half2_t*)((char*)vB2 + wbyte) =
            h2cvt(fmaf(htd, k0, hj0), fmaf(htd, k1, hj1));
      block_sync_lds();
      // stage 3: k3 = f(h + td/2 k2)
      mv(vB2, wodeH, p0, p1);
      k0 = ftanh(p0 + bo0); k1 = ftanh(p1 + bo1);
      ks0 = fmaf(2.f, k0, ks0); ks1 = fmaf(2.f, k1, ks1);
      if (kk == 0)
        *(half2_t*)((char*)vA2 + wbyte) =
            h2cvt(fmaf(td, k0, hj0), fmaf(td, k1, hj1));
      block_sync_lds();
      // stage 4: k4 = f(h + td k3); h += td/6 (k1+2k2+2k3+k4)
      mv(vA2, wodeH, p0, p1);
      k0 = ftanh(p0 + bo0); k1 = ftanh(p1 + bo1);
      ks0 += k0; ks1 += k1;
      hj0 = fmaf(td * (1.f / 6.f), ks0, hj0);
      hj1 = fmaf(td * (1.f / 6.f), ks1, hj1);
      if (kk == 0)
        *(half2_t*)((char*)vB2 + wbyte) = h2cvt(hj0, hj1);
      block_sync_lds();   // publishes vB2 (h_evolved)
    } else {
      block_sync_lds();   // t==0: publish xh/xs0f (vB2 already zeros)
      if (doGru) xpartials();
    }

    // ---- GRU (skipped entirely when this batch has no observation) ----
    if (doGru) {
      half2_t v2[32];
      #pragma unroll
      for (int q = 0; q < 8; ++q) {
        const half8_t x8 = *(const half8_t*)((const char*)vB2 + 128 * kk + 16 * q);
        v2[4*q+0] = __builtin_shufflevector(x8, x8, 0, 1);
        v2[4*q+1] = __builtin_shufflevector(x8, x8, 2, 3);
        v2[4*q+2] = __builtin_shufflevector(x8, x8, 4, 5);
        v2[4*q+3] = __builtin_shufflevector(x8, x8, 6, 7);
      }
      float rp0 = rxp0, rp1 = rxp1, zp0 = zxp0, zp1 = zxp1;
      float gp0 = 0.f, gp1 = 0.f, xp0 = xxp0, xp1 = xxp1;
      #pragma unroll
      for (int i = 0; i < 32; ++i) {
        rp0 = fdot2h(v2[i], wrhH[2*i],   rp0);
        rp1 = fdot2h(v2[i], wrhH[2*i+1], rp1);
        zp0 = fdot2h(v2[i], wzhH[2*i],   zp0);
        zp1 = fdot2h(v2[i], wzhH[2*i+1], zp1);
        gp0 = fdot2h(v2[i], whnH[2*i],   gp0);
        gp1 = fdot2h(v2[i], whnH[2*i+1], gp1);
      }
      rp0 = red2(rp0); rp1 = red2(rp1);
      zp0 = red2(zp0); zp1 = red2(zp1);
      gp0 = red2(gp0); gp1 = red2(gp1);
      xp0 = red2(xp0); xp1 = red2(xp1);
      const float r0 = fsig(rp0 + br0), r1 = fsig(rp1 + br1);
      const float z0 = fsig(zp0 + bz0), z1 = fsig(zp1 + bz1);
      const float n0 = ftanh(xp0 + bx0 + (gp0 + bh0) * r0);
      const float n1 = ftanh(xp1 + bx1 + (gp1 + bh1) * r1);
      hj0 = fmaf(z0, hj0 - n0, n0);
      hj1 = fmaf(z1, hj1 - n1, n1);
      if (kk == 0)
        *(half2_t*)((char*)hS2 + wbyte) = h2cvt(hj0, hj1);
    } else {
      if (tid == 0 && (flg & 1)) dtv += xdelta;   // dt += Xi[:,0] (no obs)
    }

    if (t == fidx) break;
    sv4 = sv4N;
    flg = flgN;
    if (doGru) block_sync_lds();   // publish hS2 before next stage 1
  }

  block_sync_lds();
  // final projection: out = h @ W_lin + b_lin (hS2 is LINEAR)
  if (tid < ODIM) {
    float acc = blin[tid];
    const _Float16* hf = (const _Float16*)hS2;
    #pragma unroll 8
    for (int q = 0; q < HID; ++q) {
      const float hv = (float)hf[q];
      acc = fmaf(hv, Wlin[q * ODIM + tid], acc);
    }
    out[b * ODIM + tid] = acc;
  }
}

extern "C" void kernel_launch(void* const* d_in, const int* in_sizes, int n_in,
                              void* d_out, int out_size, void* d_ws, size_t ws_size,
                              hipStream_t stream) {
  const float* times = (const float*)d_in[0];
  const float* ca   = (const float*)d_in[1];
  const float* cb   = (const float*)d_in[2];
  const float* cc2  = (const float*)d_in[3];
  const float* cd   = (const float*)d_in[4];
  const int*   fidx = (const int*)d_in[5];
  const float* Wr   = (const float*)d_in[6];
  const float* br   = (const float*)d_in[7];
  const float* Wz   = (const float*)d_in[8];
  const float* bz   = (const float*)d_in[9];
  const float* Wxn  = (const float*)d_in[10];
  const float* bxn  = (const float*)d_in[11];
  const float* Whn  = (const float*)d_in[12];
  const float* bhn  = (const float*)d_in[13];
  const float* Wode = (const float*)d_in[14];
  const float* bode = (const float*)d_in[15];
  const float* Wlin = (const float*)d_in[16];
  const float* blin = (const float*)d_in[17];
  float* out = (float*)d_out;

  char* ws = (char*)d_ws;
  float4* si = (float4*)ws;                                     // TT*16 B
  int* anyobs = (int*)(ws + TT * 16);                           // TT*4 B
  unsigned char* obs = (unsigned char*)(ws + TT * 16 + TT * 4); // BB*TT B

  prep0<<<1, TT, 0, stream>>>(times, si, anyobs);
  prep_obs<<<(BB * TT) / 8, 256, 0, stream>>>(ca, cb, cc2, cd, si, anyobs, obs);
  ode_main<<<BB, 128, 0, stream>>>(ca, cb, cc2, cd, fidx, Wr, br, Wz, bz,
                                   Wxn, bxn, Whn, bhn, Wode, bode, Wlin, blin,
                                   si, anyobs, obs, out);
}

// Round 15
// 904.472 us; speedup vs baseline: 1.3661x; 1.3661x over previous
//
#include <hip/hip_runtime.h>
#include <string.h>

#define TT 512
#define BB 256
#define CC 65
#define HALFC 32
#define HID 128
#define ODIM 10

typedef _Float16 half2_t __attribute__((ext_vector_type(2)));
typedef _Float16 half8_t __attribute__((ext_vector_type(8)));

// tanh(x) = 2/(1+e^{-2x}) - 1
__device__ __forceinline__ float ftanh(float x) {
  float u = __builtin_amdgcn_exp2f(x * -2.885390082f);
  return fmaf(2.f, __builtin_amdgcn_rcpf(1.f + u), -1.f);
}
// sigmoid(x) = 1/(1+e^{-x})
__device__ __forceinline__ float fsig(float x) {
  float u = __builtin_amdgcn_exp2f(x * -1.442695041f);
  return __builtin_amdgcn_rcpf(1.f + u);
}

// pack two f32 -> half2 (v_cvt_pkrtz_f16_f32)
__device__ __forceinline__ half2_t h2cvt(float a, float b) {
  auto r = __builtin_amdgcn_cvt_pkrtz(a, b);
  half2_t o;
  memcpy(&o, &r, sizeof(o));
  return o;
}

__device__ __forceinline__ float fdot2h(half2_t a, half2_t b, float c) {
  return __builtin_amdgcn_fdot2(a, b, c, false);
}

template <int CTRL>
__device__ __forceinline__ float dpp_add(float x) {
  return x + __int_as_float(__builtin_amdgcn_update_dpp(
      0, __float_as_int(x), CTRL, 0xF, 0xF, true));
}
// 4-lane subgroup sum via row_shl: dest[i] = sum src[i..i+3]; valid (lane&3)==0.
__device__ __forceinline__ float red4(float x) {
  x = dpp_add<0x101>(x);  // row_shl:1
  x = dpp_add<0x102>(x);  // row_shl:2
  return x;
}

// Raw barrier: drain LDS ops, no vmcnt drain (global loads stay in flight).
__device__ __forceinline__ void block_sync_lds() {
  asm volatile("s_waitcnt lgkmcnt(0)" ::: "memory");
  __builtin_amdgcn_s_barrier();
  asm volatile("" ::: "memory");
}
__device__ __forceinline__ void vm_wait0() {
  asm volatile("s_waitcnt vmcnt(0)" ::: "memory");
}

// Per-t scalars: idx (int bits), fr, td, tsub
__global__ void prep0(const float* __restrict__ times, float4* __restrict__ si,
                      int* __restrict__ anyobs) {
  __shared__ float ts[TT];
  int t = threadIdx.x;
  ts[t] = times[t];
  __syncthreads();
  float tv = ts[t];
  int cnt = 0;
  for (int jj = 0; jj < TT; ++jj) cnt += (tv > ts[jj]) ? 1 : 0;
  int idx = cnt - 1;
  idx = min(max(idx, 0), TT - 2);
  float4 o;
  o.x = __int_as_float(idx);
  o.y = tv - ts[idx];
  o.z = (t == 0) ? 0.f : (tv - ts[t - 1]);
  o.w = (t == 0) ? ts[0] : ts[t - 1];
  si[t] = o;
  anyobs[t] = 0;
}

// obs[b,t] = max over diffed channels 1..32 > 0.5 ; anyobs[t] = OR over b
__global__ void prep_obs(const float* __restrict__ ca, const float* __restrict__ cb,
                         const float* __restrict__ cc2, const float* __restrict__ cd,
                         const float4* __restrict__ si, int* __restrict__ anyobs,
                         unsigned char* __restrict__ obs) {
  int grp = blockIdx.x * (blockDim.x >> 5) + (threadIdx.x >> 5);
  int lane = threadIdx.x & 31;
  int t = grp & (TT - 1);
  int b = grp / TT;
  int ch = 1 + lane;
  float4 s = si[t];
  int idx = __float_as_int(s.x);
  float fr = s.y;
  size_t base = ((size_t)b * (TT - 1) + idx) * CC + ch;
  float f3 = fr / 3.f;
  float v = ca[base] + (cb[base] + (0.5f * cc2[base] + cd[base] * f3) * fr) * fr;
  float D = v;
  if (t >= 1) {
    float4 sp = si[t - 1];
    int idxp = __float_as_int(sp.x);
    float frp = sp.y;
    size_t basep = ((size_t)b * (TT - 1) + idxp) * CC + ch;
    float f3p = frp / 3.f;
    float vp = ca[basep] + (cb[basep] + (0.5f * cc2[basep] + cd[basep] * f3p) * frp) * frp;
    D = v - vp;
  }
  float m = D;
  #pragma unroll
  for (int off = 16; off >= 1; off >>= 1) m = fmaxf(m, __shfl_xor(m, off));
  if (lane == 0) {
    unsigned char o = (m > 0.5f) ? (unsigned char)1 : (unsigned char)0;
    obs[(size_t)b * TT + t] = o;
    if (o) atomicOr(&anyobs[t], 1);
  }
}

// One block per batch element. 256 threads = 4 waves. Lane (p=lane>>2, kk=lane&3)
// owns output pair s = wv*16+p over k-slice [32kk, 32kk+32). f16 weights+state,
// v_dot2; x channel 0 in f32. Schedule: spline at loop top (prev-step prefetch),
// x-matvec partials in stage-2 shadow, GRU skipped when ob==0 (block-uniform).
__launch_bounds__(256, 1)
__global__ void ode_main(
    const float* __restrict__ ca, const float* __restrict__ cb,
    const float* __restrict__ cc2, const float* __restrict__ cd,
    const int* __restrict__ final_index,
    const float* __restrict__ Wr, const float* __restrict__ br,
    const float* __restrict__ Wz, const float* __restrict__ bz,
    const float* __restrict__ Wxn, const float* __restrict__ bxn,
    const float* __restrict__ Whn, const float* __restrict__ bhn,
    const float* __restrict__ Wode, const float* __restrict__ bode,
    const float* __restrict__ Wlin, const float* __restrict__ blin,
    const float4* __restrict__ si, const int* __restrict__ anyobs,
    const unsigned char* __restrict__ obsArr,
    float* __restrict__ out)
{
  __shared__ alignas(16) half2_t hS2[HID / 2];
  __shared__ alignas(16) half2_t vA2[HID / 2];
  __shared__ alignas(16) half2_t vB2[HID / 2];
  __shared__ alignas(16) _Float16 xh[HALFC];
  __shared__ float xs0f;
  __shared__ alignas(16) float4 siL[TT];
  __shared__ unsigned char flagL[TT];

  const int tid = threadIdx.x;
  const int b = blockIdx.x;
  const int lane = tid & 63;
  const int wv = tid >> 6;       // 0..3
  const int p = lane >> 2;       // 0..15
  const int kk = lane & 3;       // 0..3
  const int s = wv * 16 + p;     // output pair 0..63
  const int j0 = 2 * s;
  const int wbyte = 4 * s;       // write byte offset (half2)

  // ---- h-matvec weights f16 ----
  half2_t wodeH[32], whnH[32], wrhH[32], wzhH[32];
  #pragma unroll
  for (int i = 0; i < 16; ++i) {
    const int r0 = 32 * kk + 2 * i, r1 = r0 + 1;
    float2 q0, q1;
    q0 = *(const float2*)&Wode[r0 * HID + j0];
    q1 = *(const float2*)&Wode[r1 * HID + j0];
    wodeH[2*i] = h2cvt(q0.x, q1.x); wodeH[2*i+1] = h2cvt(q0.y, q1.y);
    q0 = *(const float2*)&Whn[r0 * HID + j0];
    q1 = *(const float2*)&Whn[r1 * HID + j0];
    whnH[2*i] = h2cvt(q0.x, q1.x); whnH[2*i+1] = h2cvt(q0.y, q1.y);
    q0 = *(const float2*)&Wr[(HALFC + r0) * HID + j0];
    q1 = *(const float2*)&Wr[(HALFC + r1) * HID + j0];
    wrhH[2*i] = h2cvt(q0.x, q1.x); wrhH[2*i+1] = h2cvt(q0.y, q1.y);
    q0 = *(const float2*)&Wz[(HALFC + r0) * HID + j0];
    q1 = *(const float2*)&Wz[(HALFC + r1) * HID + j0];
    wzhH[2*i] = h2cvt(q0.x, q1.x); wzhH[2*i+1] = h2cvt(q0.y, q1.y);
  }
  // x-part weights f16 over channels [8kk, 8kk+8)
  half2_t wrxH[8], wzxH[8], wxnH[8];
  #pragma unroll
  for (int i = 0; i < 4; ++i) {
    const int c0 = 8 * kk + 2 * i, c1 = c0 + 1;
    float2 q0, q1;
    q0 = *(const float2*)&Wr[c0 * HID + j0];
    q1 = *(const float2*)&Wr[c1 * HID + j0];
    wrxH[i] = h2cvt(q0.x, q1.x); wrxH[4+i] = h2cvt(q0.y, q1.y);
    q0 = *(const float2*)&Wz[c0 * HID + j0];
    q1 = *(const float2*)&Wz[c1 * HID + j0];
    wzxH[i] = h2cvt(q0.x, q1.x); wzxH[4+i] = h2cvt(q0.y, q1.y);
    q0 = *(const float2*)&Wxn[c0 * HID + j0];
    q1 = *(const float2*)&Wxn[c1 * HID + j0];
    wxnH[i] = h2cvt(q0.x, q1.x); wxnH[4+i] = h2cvt(q0.y, q1.y);
  }
  // channel 0 (dt channel, large): zero f16 weight, add in f32
  float wr0a = 0.f, wr0b = 0.f, wz0a = 0.f, wz0b = 0.f, wx0a = 0.f, wx0b = 0.f;
  if (kk == 0) {
    wrxH[0][0] = (_Float16)0.f; wrxH[4][0] = (_Float16)0.f;
    wzxH[0][0] = (_Float16)0.f; wzxH[4][0] = (_Float16)0.f;
    wxnH[0][0] = (_Float16)0.f; wxnH[4][0] = (_Float16)0.f;
    wr0a = Wr[j0];  wr0b = Wr[j0 + 1];
    wz0a = Wz[j0];  wz0b = Wz[j0 + 1];
    wx0a = Wxn[j0]; wx0b = Wxn[j0 + 1];
  }
  float bo0, bo1, bh0, bh1, br0, br1, bz0, bz1, bx0, bx1;
  { float2 q;
    q = *(const float2*)&bode[j0]; bo0 = q.x; bo1 = q.y;
    q = *(const float2*)&bhn [j0]; bh0 = q.x; bh1 = q.y;
    q = *(const float2*)&br  [j0]; br0 = q.x; br1 = q.y;
    q = *(const float2*)&bz  [j0]; bz0 = q.x; bz1 = q.y;
    q = *(const float2*)&bxn [j0]; bx0 = q.x; bx1 = q.y;
  }
  const int fidx = final_index[b];

  // ---- stage per-step metadata into LDS (one-time; 2 sweeps of 256) ----
  #pragma unroll
  for (int it = 0; it < 2; ++it) {
    const int tt = tid + it * 256;
    siL[tt] = si[tt];
    const int ao = anyobs[tt];
    const unsigned char o = obsArr[(size_t)b * TT + tt];
    flagL[tt] = (unsigned char)((ao ? 1 : 0) | (o ? 2 : 0));
  }
  if (tid < HID / 2) {
    const half2_t z2 = {(_Float16)0.f, (_Float16)0.f};
    hS2[tid] = z2; vA2[tid] = z2; vB2[tid] = z2;
  }
  if (tid < HALFC) xh[tid] = (_Float16)0.f;
  if (tid == 0) xs0f = 0.f;
  float hj0 = 0.f, hj1 = 0.f;  // fp32 master h, valid on kk==0 lanes
  float dtv = 0.f;             // valid on tid==0
  block_sync_lds();

  // matvec over linear f16 LDS vector: 4 b128 reads, 32 dot2, red4.
  auto mv = [&](const half2_t* __restrict__ buf, const half2_t (&w)[32],
                float& o0, float& o1) {
    half2_t v2[16];
    #pragma unroll
    for (int q = 0; q < 4; ++q) {
      const half8_t x8 = *(const half8_t*)((const char*)buf + 64 * kk + 16 * q);
      v2[4*q+0] = __builtin_shufflevector(x8, x8, 0, 1);
      v2[4*q+1] = __builtin_shufflevector(x8, x8, 2, 3);
      v2[4*q+2] = __builtin_shufflevector(x8, x8, 4, 5);
      v2[4*q+3] = __builtin_shufflevector(x8, x8, 6, 7);
    }
    float a0 = 0.f, a1 = 0.f, b0 = 0.f, b1 = 0.f;
    #pragma unroll
    for (int i = 0; i < 8; ++i) {
      a0 = fdot2h(v2[i],     w[2*i],       a0);
      a1 = fdot2h(v2[i],     w[2*i+1],     a1);
      b0 = fdot2h(v2[8 + i], w[2*(8+i)],   b0);
      b1 = fdot2h(v2[8 + i], w[2*(8+i)+1], b1);
    }
    o0 = red4(a0 + b0);
    o1 = red4(a1 + b1);
  };

  const int xch = wv * 8 + lane;   // valid when lane < 8
  const bool xlane = (lane < 8);

  float4 sv4 = siL[0];
  int flg = flagL[0];

  // issue x-coeff loads for t=0
  float xa = 0.f, xb = 0.f, xc = 0.f, xd = 0.f;
  float ya = 0.f, yb = 0.f, yc = 0.f, yd = 0.f;
  if (xlane) {
    const size_t base = ((size_t)b * (TT - 1) + __float_as_int(sv4.x)) * CC;
    const int ch = 33 + xch;
    xa = ca[base + ch]; xb = cb[base + ch]; xc = cc2[base + ch]; xd = cd[base + ch];
    if (tid == 0) { ya = ca[base]; yb = cb[base]; yc = cc2[base]; yd = cd[base]; }
  }

  for (int t = 0; ; ++t) {
    const float fr = sv4.y, td = sv4.z, tsub = sv4.w;
    const bool doGru = (flg & 2) != 0;   // block-uniform

    // ---- loop top: spline for step t (loads issued last iter) ----
    float xdelta = 0.f;
    vm_wait0();
    if (xlane) {
      const float f3 = fr * (1.f / 3.f);
      float sv = xa + (xb + (0.5f * xc + xd * f3) * fr) * fr;
      if (tid == 0) {
        const float s0 = ya + (yb + (0.5f * yc + yd * f3) * fr) * fr;
        xdelta = s0 - tsub;
        sv += dtv;       // Xp[:,0] += dt (dtv final from step t-1)
        xs0f = sv;
      }
      xh[xch] = (_Float16)sv;
    }

    // ---- prefetch next step's metadata + issue next x-coeff loads ----
    const int tn = (t < TT - 1) ? t + 1 : t;
    const float4 sv4N = siL[tn];
    const int flgN = flagL[tn];
    if (xlane) {
      const size_t base = ((size_t)b * (TT - 1) + __float_as_int(sv4N.x)) * CC;
      const int ch = 33 + xch;
      xa = ca[base + ch]; xb = cb[base + ch]; xc = cc2[base + ch]; xd = cd[base + ch];
      if (tid == 0) { ya = ca[base]; yb = cb[base]; yc = cc2[base]; yd = cd[base]; }
    }

    // x-matvec partials (computed in stage-2 shadow when t>0)
    float rxp0 = 0.f, rxp1 = 0.f, zxp0 = 0.f, zxp1 = 0.f, xxp0 = 0.f, xxp1 = 0.f;

    if (t > 0) {
      const float htd = 0.5f * td;
      float p0, p1, k0, k1, ks0, ks1;
      // stage 1: k1 = f(h)
      mv(hS2, wodeH, p0, p1);
      k0 = ftanh(p0 + bo0); k1 = ftanh(p1 + bo1);
      ks0 = k0; ks1 = k1;
      if (kk == 0)
        *(half2_t*)((char*)vA2 + wbyte) =
            h2cvt(fmaf(htd, k0, hj0), fmaf(htd, k1, hj1));
      block_sync_lds();   // publishes vA2 AND xh/xs0f
      // x-partials in stage-2's shadow
      if (doGru) {
        const half8_t x8 = *(const half8_t*)((const char*)xh + 16 * kk);
        half2_t xv2[4];
        xv2[0] = __builtin_shufflevector(x8, x8, 0, 1);
        xv2[1] = __builtin_shufflevector(x8, x8, 2, 3);
        xv2[2] = __builtin_shufflevector(x8, x8, 4, 5);
        xv2[3] = __builtin_shufflevector(x8, x8, 6, 7);
        #pragma unroll
        for (int i = 0; i < 4; ++i) {
          rxp0 = fdot2h(xv2[i], wrxH[i],   rxp0);
          rxp1 = fdot2h(xv2[i], wrxH[4+i], rxp1);
          zxp0 = fdot2h(xv2[i], wzxH[i],   zxp0);
          zxp1 = fdot2h(xv2[i], wzxH[4+i], zxp1);
          xxp0 = fdot2h(xv2[i], wxnH[i],   xxp0);
          xxp1 = fdot2h(xv2[i], wxnH[4+i], xxp1);
        }
        if (kk == 0) {
          const float x0 = xs0f;
          rxp0 = fmaf(x0, wr0a, rxp0); rxp1 = fmaf(x0, wr0b, rxp1);
          zxp0 = fmaf(x0, wz0a, zxp0); zxp1 = fmaf(x0, wz0b, zxp1);
          xxp0 = fmaf(x0, wx0a, xxp0); xxp1 = fmaf(x0, wx0b, xxp1);
        }
      }
      // stage 2: k2 = f(h + td/2 k1)
      mv(vA2, wodeH, p0, p1);
      k0 = ftanh(p0 + bo0); k1 = ftanh(p1 + bo1);
      ks0 = fmaf(2.f, k0, ks0); ks1 = fmaf(2.f, k1, ks1);
      if (kk == 0)
        *(half2_t*)((char*)vB2 + wbyte) =
            h2cvt(fmaf(htd, k0, hj0), fmaf(htd, k1, hj1));
      block_sync_lds();
      // stage 3: k3 = f(h + td/2 k2)
      mv(vB2, wodeH, p0, p1);
      k0 = ftanh(p0 + bo0); k1 = ftanh(p1 + bo1);
      ks0 = fmaf(2.f, k0, ks0); ks1 = fmaf(2.f, k1, ks1);
      if (kk == 0)
        *(half2_t*)((char*)vA2 + wbyte) =
            h2cvt(fmaf(td, k0, hj0), fmaf(td, k1, hj1));
      block_sync_lds();
      // stage 4: k4 = f(h + td k3); h += td/6 (k1+2k2+2k3+k4)
      mv(vA2, wodeH, p0, p1);
      k0 = ftanh(p0 + bo0); k1 = ftanh(p1 + bo1);
      ks0 += k0; ks1 += k1;
      hj0 = fmaf(td * (1.f / 6.f), ks0, hj0);
      hj1 = fmaf(td * (1.f / 6.f), ks1, hj1);
      if (kk == 0)
        *(half2_t*)((char*)vB2 + wbyte) = h2cvt(hj0, hj1);
      block_sync_lds();   // publishes vB2 (h_evolved)
    } else {
      block_sync_lds();   // t==0: publish xh/xs0f (vB2 already zeros)
      if (doGru) {
        const half8_t x8 = *(const half8_t*)((const char*)xh + 16 * kk);
        half2_t xv2[4];
        xv2[0] = __builtin_shufflevector(x8, x8, 0, 1);
        xv2[1] = __builtin_shufflevector(x8, x8, 2, 3);
        xv2[2] = __builtin_shufflevector(x8, x8, 4, 5);
        xv2[3] = __builtin_shufflevector(x8, x8, 6, 7);
        #pragma unroll
        for (int i = 0; i < 4; ++i) {
          rxp0 = fdot2h(xv2[i], wrxH[i],   rxp0);
          rxp1 = fdot2h(xv2[i], wrxH[4+i], rxp1);
          zxp0 = fdot2h(xv2[i], wzxH[i],   zxp0);
          zxp1 = fdot2h(xv2[i], wzxH[4+i], zxp1);
          xxp0 = fdot2h(xv2[i], wxnH[i],   xxp0);
          xxp1 = fdot2h(xv2[i], wxnH[4+i], xxp1);
        }
        if (kk == 0) {
          const float x0 = xs0f;
          rxp0 = fmaf(x0, wr0a, rxp0); rxp1 = fmaf(x0, wr0b, rxp1);
          zxp0 = fmaf(x0, wz0a, zxp0); zxp1 = fmaf(x0, wz0b, zxp1);
          xxp0 = fmaf(x0, wx0a, xxp0); xxp1 = fmaf(x0, wx0b, xxp1);
        }
      }
    }

    // ---- GRU (skipped entirely when this batch has no observation) ----
    if (doGru) {
      half2_t v2[16];
      #pragma unroll
      for (int q = 0; q < 4; ++q) {
        const half8_t x8 = *(const half8_t*)((const char*)vB2 + 64 * kk + 16 * q);
        v2[4*q+0] = __builtin_shufflevector(x8, x8, 0, 1);
        v2[4*q+1] = __builtin_shufflevector(x8, x8, 2, 3);
        v2[4*q+2] = __builtin_shufflevector(x8, x8, 4, 5);
        v2[4*q+3] = __builtin_shufflevector(x8, x8, 6, 7);
      }
      float rp0 = rxp0, rp1 = rxp1, zp0 = zxp0, zp1 = zxp1;
      float gp0 = 0.f, gp1 = 0.f, xp0 = xxp0, xp1 = xxp1;
      #pragma unroll
      for (int i = 0; i < 16; ++i) {
        rp0 = fdot2h(v2[i], wrhH[2*i],   rp0);
        rp1 = fdot2h(v2[i], wrhH[2*i+1], rp1);
        zp0 = fdot2h(v2[i], wzhH[2*i],   zp0);
        zp1 = fdot2h(v2[i], wzhH[2*i+1], zp1);
        gp0 = fdot2h(v2[i], whnH[2*i],   gp0);
        gp1 = fdot2h(v2[i], whnH[2*i+1], gp1);
      }
      rp0 = red4(rp0); rp1 = red4(rp1);
      zp0 = red4(zp0); zp1 = red4(zp1);
      gp0 = red4(gp0); gp1 = red4(gp1);
      xp0 = red4(xp0); xp1 = red4(xp1);
      const float r0 = fsig(rp0 + br0), r1 = fsig(rp1 + br1);
      const float z0 = fsig(zp0 + bz0), z1 = fsig(zp1 + bz1);
      const float n0 = ftanh(xp0 + bx0 + (gp0 + bh0) * r0);
      const float n1 = ftanh(xp1 + bx1 + (gp1 + bh1) * r1);
      hj0 = fmaf(z0, hj0 - n0, n0);   // apply == doGru (aob implied by ob)
      hj1 = fmaf(z1, hj1 - n1, n1);
      if (kk == 0)
        *(half2_t*)((char*)hS2 + wbyte) = h2cvt(hj0, hj1);
    } else {
      if (tid == 0 && (flg & 1)) dtv += xdelta;   // dt += Xi[:,0] (no obs here)
    }

    if (t == fidx) break;
    sv4 = sv4N;
    flg = flgN;
    if (doGru) block_sync_lds();   // publish hS2 before next stage 1
  }

  block_sync_lds();
  // final projection: out = h @ W_lin + b_lin (hS2 is LINEAR)
  if (tid < ODIM) {
    float acc = blin[tid];
    const _Float16* hf = (const _Float16*)hS2;
    #pragma unroll 8
    for (int q = 0; q < HID; ++q) {
      const float hv = (float)hf[q];
      acc = fmaf(hv, Wlin[q * ODIM + tid], acc);
    }
    out[b * ODIM + tid] = acc;
  }
}

extern "C" void kernel_launch(void* const* d_in, const int* in_sizes, int n_in,
                              void* d_out, int out_size, void* d_ws, size_t ws_size,
                              hipStream_t stream) {
  const float* times = (const float*)d_in[0];
  const float* ca   = (const float*)d_in[1];
  const float* cb   = (const float*)d_in[2];
  const float* cc2  = (const float*)d_in[3];
  const float* cd   = (const float*)d_in[4];
  const int*   fidx = (const int*)d_in[5];
  const float* Wr   = (const float*)d_in[6];
  const float* br   = (const float*)d_in[7];
  const float* Wz   = (const float*)d_in[8];
  const float* bz   = (const float*)d_in[9];
  const float* Wxn  = (const float*)d_in[10];
  const float* bxn  = (const float*)d_in[11];
  const float* Whn  = (const float*)d_in[12];
  const float* bhn  = (const float*)d_in[13];
  const float* Wode = (const float*)d_in[14];
  const float* bode = (const float*)d_in[15];
  const float* Wlin = (const float*)d_in[16];
  const float* blin = (const float*)d_in[17];
  float* out = (float*)d_out;

  char* ws = (char*)d_ws;
  float4* si = (float4*)ws;                                     // TT*16 B
  int* anyobs = (int*)(ws + TT * 16);                           // TT*4 B
  unsigned char* obs = (unsigned char*)(ws + TT * 16 + TT * 4); // BB*TT B

  prep0<<<1, TT, 0, stream>>>(times, si, anyobs);
  prep_obs<<<(BB * TT) / 8, 256, 0, stream>>>(ca, cb, cc2, cd, si, anyobs, obs);
  ode_main<<<BB, 256, 0, stream>>>(ca, cb, cc2, cd, fidx, Wr, br, Wz, bz,
                                   Wxn, bxn, Whn, bhn, Wode, bode, Wlin, blin,
                                   si, anyobs, obs, out);
}